// Round 1
// baseline (136.302 us; speedup 1.0000x reference)
//
#include <hip/hip_runtime.h>

// RBF kernel: out[n,m] = exp(-0.5 * max(||A_n||^2 + ||B_m||^2 - 2 A_n.B_m, 0))
// N=M=8192, D=64, fp32 in/out.
// 128x128 tile / 256 threads / 8x8 micro-tile, transposed LDS staging.

constexpr int N = 8192;
constexpr int M = 8192;
constexpr int D = 64;
constexpr int BM = 128;
constexpr int BN = 128;

__global__ __launch_bounds__(256, 2) void rbf_tile_kernel_58720792871618(
    const float* __restrict__ A, const float* __restrict__ B, float* __restrict__ C)
{
    __shared__ float As[D][BM];   // transposed: As[d][row-in-tile]
    __shared__ float Bs[D][BN];
    __shared__ float nA[BM];
    __shared__ float nB[BN];

    const int tid  = threadIdx.x;
    const int row0 = blockIdx.y * BM;
    const int col0 = blockIdx.x * BN;

    // ---- stage tiles (transposed). thread t: row t/2, col-half (t&1)*32 ----
    {
        const int r  = tid >> 1;
        const int c0 = (tid & 1) * 32;
        const float4* __restrict__ sa =
            reinterpret_cast<const float4*>(A + (size_t)(row0 + r) * D + c0);
        const float4* __restrict__ sb =
            reinterpret_cast<const float4*>(B + (size_t)(col0 + r) * D + c0);
        #pragma unroll
        for (int k = 0; k < 8; ++k) {
            const float4 v = sa[k];
            const int c = c0 + 4 * k;
            As[c + 0][r] = v.x; As[c + 1][r] = v.y;
            As[c + 2][r] = v.z; As[c + 3][r] = v.w;
        }
        #pragma unroll
        for (int k = 0; k < 8; ++k) {
            const float4 v = sb[k];
            const int c = c0 + 4 * k;
            Bs[c + 0][r] = v.x; Bs[c + 1][r] = v.y;
            Bs[c + 2][r] = v.z; Bs[c + 3][r] = v.w;
        }
    }
    __syncthreads();

    // ---- per-row squared norms (threads 0..127 -> A rows, 128..255 -> B rows) ----
    if (tid < BM) {
        float s = 0.f;
        #pragma unroll
        for (int d = 0; d < D; ++d) { const float v = As[d][tid]; s = fmaf(v, v, s); }
        nA[tid] = s;
    } else {
        const int r = tid - BM;
        float s = 0.f;
        #pragma unroll
        for (int d = 0; d < D; ++d) { const float v = Bs[d][r]; s = fmaf(v, v, s); }
        nB[r] = s;
    }
    __syncthreads();

    // ---- 8x8 micro-tile dot-product accumulation ----
    const int tx = tid & 15;
    const int ty = tid >> 4;
    const int ar = ty * 8;   // A-row base within tile
    const int bc = tx * 8;   // B-row (output col) base within tile

    float acc[8][8];
    #pragma unroll
    for (int i = 0; i < 8; ++i)
        #pragma unroll
        for (int j = 0; j < 8; ++j) acc[i][j] = 0.f;

    #pragma unroll 4
    for (int d = 0; d < D; ++d) {
        const float4 a0 = *reinterpret_cast<const float4*>(&As[d][ar]);
        const float4 a1 = *reinterpret_cast<const float4*>(&As[d][ar + 4]);
        const float4 b0 = *reinterpret_cast<const float4*>(&Bs[d][bc]);
        const float4 b1 = *reinterpret_cast<const float4*>(&Bs[d][bc + 4]);
        const float a[8] = {a0.x, a0.y, a0.z, a0.w, a1.x, a1.y, a1.z, a1.w};
        const float b[8] = {b0.x, b0.y, b0.z, b0.w, b1.x, b1.y, b1.z, b1.w};
        #pragma unroll
        for (int i = 0; i < 8; ++i)
            #pragma unroll
            for (int j = 0; j < 8; ++j)
                acc[i][j] = fmaf(a[i], b[j], acc[i][j]);
    }

    // ---- epilogue: sqdist -> exp -> store (two float4 per row) ----
    #pragma unroll
    for (int i = 0; i < 8; ++i) {
        const float na = nA[ar + i];
        float o[8];
        #pragma unroll
        for (int j = 0; j < 8; ++j) {
            float sq = na + nB[bc + j] - 2.0f * acc[i][j];
            sq = fmaxf(sq, 0.0f);
            o[j] = __expf(-0.5f * sq);
        }
        float4* dst = reinterpret_cast<float4*>(
            C + (size_t)(row0 + ar + i) * M + (col0 + bc));
        dst[0] = make_float4(o[0], o[1], o[2], o[3]);
        dst[1] = make_float4(o[4], o[5], o[6], o[7]);
    }
}

extern "C" void kernel_launch(void* const* d_in, const int* /*in_sizes*/, int /*n_in*/,
                              void* d_out, int /*out_size*/, void* /*d_ws*/, size_t /*ws_size*/,
                              hipStream_t stream)
{
    const float* A = (const float*)d_in[0];   // input_1 [N, D]
    const float* B = (const float*)d_in[1];   // input_2 [M, D]
    float* C = (float*)d_out;                 // [N, M]
    dim3 grid(M / BN, N / BM);
    rbf_tile_kernel_58720792871618<<<grid, 256, 0, stream>>>(A, B, C);
}

// Round 2
// 55.074 us; speedup vs baseline: 2.4749x; 2.4749x over previous
//
#include <hip/hip_runtime.h>

// RBF: out[n,m] = exp(-0.5 * max(||A_n||^2 + ||B_m||^2 - 2 A_n.B_m, 0))
// N=M=8192, D=64, fp32 in/out.
// fp16 MFMA cross-term (16x16x32_f16), exact fp32 norms, exp2 epilogue.
// 128x128 tile / 256 threads (4 waves, 2x2 of 64x64), XOR-swizzled LDS.

constexpr int Mdim = 8192;
constexpr int D    = 64;
constexpr int BM   = 128;
constexpr int BN   = 128;
constexpr float NEG_HALF_L2E = -0.72134752044448170f; // -0.5*log2(e)
constexpr float L2E          =  1.44269504088896340f; //  log2(e)

typedef __attribute__((ext_vector_type(8))) _Float16 f16x8;
typedef __attribute__((ext_vector_type(4))) float    f32x4;

__global__ __launch_bounds__(256, 3) void rbf_mfma_58720792871618(
    const float* __restrict__ A, const float* __restrict__ B, float* __restrict__ C)
{
    __shared__ _Float16 Ash[BM * D];   // row-major, 128 B/row, XOR-swizzled slots
    __shared__ _Float16 Bsh[BN * D];
    __shared__ float pA[BM];           // -0.5*log2e * ||row||^2
    __shared__ float pB[BN];

    const int tid  = threadIdx.x;
    const int lane = tid & 63;
    const int wid  = tid >> 6;
    const int row0 = blockIdx.y * BM;
    const int col0 = blockIdx.x * BN;

    // ---------------- stage: fp32 -> fp16 into swizzled LDS + fp32 norms ----------------
    {
        const int r  = tid >> 1;           // tile row 0..127 (A and B)
        const int c0 = (tid & 1) * 32;     // column half
        const float4* ga = reinterpret_cast<const float4*>(A + (size_t)(row0 + r) * D + c0);
        const float4* gb = reinterpret_cast<const float4*>(B + (size_t)(col0 + r) * D + c0);

        float sa = 0.f, sb = 0.f;
        f16x8 ha[4], hb[4];
        #pragma unroll
        for (int k = 0; k < 8; ++k) {
            const float4 v = ga[k];
            sa = fmaf(v.x, v.x, fmaf(v.y, v.y, fmaf(v.z, v.z, fmaf(v.w, v.w, sa))));
            const int t = k >> 1, o = (k & 1) * 4;
            ha[t][o + 0] = (_Float16)v.x; ha[t][o + 1] = (_Float16)v.y;
            ha[t][o + 2] = (_Float16)v.z; ha[t][o + 3] = (_Float16)v.w;
        }
        #pragma unroll
        for (int k = 0; k < 8; ++k) {
            const float4 v = gb[k];
            sb = fmaf(v.x, v.x, fmaf(v.y, v.y, fmaf(v.z, v.z, fmaf(v.w, v.w, sb))));
            const int t = k >> 1, o = (k & 1) * 4;
            hb[t][o + 0] = (_Float16)v.x; hb[t][o + 1] = (_Float16)v.y;
            hb[t][o + 2] = (_Float16)v.z; hb[t][o + 3] = (_Float16)v.w;
        }

        char* abase = reinterpret_cast<char*>(Ash) + r * 128;
        char* bbase = reinterpret_cast<char*>(Bsh) + r * 128;
        #pragma unroll
        for (int t = 0; t < 4; ++t) {
            const int sw = (c0 * 2 + t * 16) ^ ((r & 7) << 4);
            *reinterpret_cast<f16x8*>(abase + sw) = ha[t];
        }
        #pragma unroll
        for (int t = 0; t < 4; ++t) {
            const int sw = (c0 * 2 + t * 16) ^ ((r & 7) << 4);
            *reinterpret_cast<f16x8*>(bbase + sw) = hb[t];
        }

        sa += __shfl_xor(sa, 1);
        sb += __shfl_xor(sb, 1);
        if ((tid & 1) == 0) { pA[r] = NEG_HALF_L2E * sa; pB[r] = NEG_HALF_L2E * sb; }
    }
    __syncthreads();

    // ---------------- MFMA: 64x64 per wave, 4x4 fragments of 16x16, K=64 ----------------
    const int wr = (wid >> 1) * 64;    // wave row base in tile
    const int wc = (wid & 1) * 64;     // wave col base in tile
    const int lr = lane & 15;          // fragment row/col
    const int kg = lane >> 4;          // k-group (and C row-quad)

    f32x4 acc[4][4] = {};

    #pragma unroll
    for (int ks = 0; ks < 2; ++ks) {
        f16x8 af[4], bf[4];
        #pragma unroll
        for (int mi = 0; mi < 4; ++mi) {
            const int row = wr + mi * 16 + lr;
            af[mi] = *reinterpret_cast<const f16x8*>(
                reinterpret_cast<const char*>(Ash) + row * 128 +
                ((ks * 64 + kg * 16) ^ ((row & 7) << 4)));
        }
        #pragma unroll
        for (int ni = 0; ni < 4; ++ni) {
            const int col = wc + ni * 16 + lr;
            bf[ni] = *reinterpret_cast<const f16x8*>(
                reinterpret_cast<const char*>(Bsh) + col * 128 +
                ((ks * 64 + kg * 16) ^ ((col & 7) << 4)));
        }
        #pragma unroll
        for (int mi = 0; mi < 4; ++mi)
            #pragma unroll
            for (int ni = 0; ni < 4; ++ni)
                acc[mi][ni] = __builtin_amdgcn_mfma_f32_16x16x32_f16(
                    af[mi], bf[ni], acc[mi][ni], 0, 0, 0);
    }

    // ---------------- epilogue: t = log2e*acc + pa + pb; out = exp2(min(t,0)) ----------------
    float pb[4];
    #pragma unroll
    for (int ni = 0; ni < 4; ++ni) pb[ni] = pB[wc + ni * 16 + lr];

    #pragma unroll
    for (int mi = 0; mi < 4; ++mi) {
        #pragma unroll
        for (int r = 0; r < 4; ++r) {
            const int lrow = wr + mi * 16 + kg * 4 + r;   // C: row=(lane>>4)*4+reg
            const float pa = pA[lrow];
            float* crow = C + (size_t)(row0 + lrow) * Mdim + (col0 + wc + lr);
            #pragma unroll
            for (int ni = 0; ni < 4; ++ni) {
                float t = fmaf(L2E, acc[mi][ni][r], pa + pb[ni]);
                t = fminf(t, 0.0f);
                crow[ni * 16] = __builtin_amdgcn_exp2f(t);
            }
        }
    }
}

extern "C" void kernel_launch(void* const* d_in, const int* /*in_sizes*/, int /*n_in*/,
                              void* d_out, int /*out_size*/, void* /*d_ws*/, size_t /*ws_size*/,
                              hipStream_t stream)
{
    const float* A = (const float*)d_in[0];   // input_1 [8192, 64]
    const float* B = (const float*)d_in[1];   // input_2 [8192, 64]
    float* C = (float*)d_out;                 // [8192, 8192]
    dim3 grid(Mdim / BN, 8192 / BM);
    rbf_mfma_58720792871618<<<grid, 256, 0, stream>>>(A, B, C);
}